// Round 2
// baseline (290.599 us; speedup 1.0000x reference)
//
#include <hip/hip_runtime.h>

typedef __bf16 bf16;
typedef __bf16 bf16x4 __attribute__((ext_vector_type(4)));
typedef __bf16 bf16x8 __attribute__((ext_vector_type(8)));
typedef float f32x4 __attribute__((ext_vector_type(4)));

#define NROWS 32768   // B*S = 32*1024
#define EMBED 512
#define CONV_C 512
#define HID 1024
#define LABELS 128

__device__ inline void async16(const void* g, void* l) {
  __builtin_amdgcn_global_load_lds(
      (const __attribute__((address_space(1))) void*)g,
      (__attribute__((address_space(3))) void*)l, 16, 0, 0);
}

// read 8 consecutive f32 from LDS, convert to bf16x8 (A/B fragment)
__device__ inline bf16x8 cvt8(const float* p) {
  f32x4 lo = *(const f32x4*)p;
  f32x4 hi = *(const f32x4*)(p + 4);
  bf16x8 r;
  r[0] = (bf16)lo[0]; r[1] = (bf16)lo[1]; r[2] = (bf16)lo[2]; r[3] = (bf16)lo[3];
  r[4] = (bf16)hi[0]; r[5] = (bf16)hi[1]; r[6] = (bf16)hi[2]; r[7] = (bf16)hi[3];
  return r;
}

// ---- prep: [K,N] f32 -> [N,K] bf16 transpose, 64x64 tiles ------------------
__global__ void transpose_cvt(const float* __restrict__ in, bf16* __restrict__ out,
                              int K, int N) {
  __shared__ float t[64][65];
  int kb = blockIdx.x * 64, nb = blockIdx.y * 64;
  for (int i = threadIdx.x; i < 4096; i += 256) {
    int r = i >> 6, c = i & 63;
    t[r][c] = in[(size_t)(kb + r) * N + nb + c];
  }
  __syncthreads();
  for (int i = threadIdx.x; i < 4096; i += 256) {
    int r = i >> 6, c = i & 63;
    out[(size_t)(nb + r) * K + kb + c] = (bf16)t[c][r];
  }
}

// ---- layer 1: h = relu(emb[tok] @ conv_w^T + conv_b), gather fused ---------
// A rows gathered from emb (fp32) via per-lane global addresses; B = conv_w
// fp32 [512,512] ([N,K], row-major). Both staged fp32, cvt->bf16 on frag read.
// 128x128 tile, 4 waves of 64x64, BK=32.
__global__ __launch_bounds__(256) void gemm1_gather(
    const int* __restrict__ tok, const float* __restrict__ emb,
    const float* __restrict__ convw, const float* __restrict__ bias,
    bf16* __restrict__ out, int M, int N, int K) {
  __shared__ __attribute__((aligned(16))) float lAf[128 * 32];
  __shared__ __attribute__((aligned(16))) float lBf[128 * 32];
  const int tid = threadIdx.x;
  const int wave = tid >> 6, lane = tid & 63;
  const int m0 = blockIdx.x * 128, n0 = blockIdx.y * 128;
  const int wm = (wave & 1) * 64, wn = (wave >> 1) * 64;
  const int lrow = lane & 15, quad = lane >> 4;
  const int slot0 = wave * 64 + lane;
  const int cs4 = (slot0 & 7) * 4;   // f32 col offset of this lane's granule
  const int rbase = slot0 >> 3;      // row of c=0 granule

  // preload token ids for the 4 A-rows this thread stages (constant over K)
  int trow[4];
#pragma unroll
  for (int c = 0; c < 4; ++c) trow[c] = tok[m0 + rbase + c * 32];

  const f32x4 zero4 = {0.f, 0.f, 0.f, 0.f};
  f32x4 acc[4][4];
#pragma unroll
  for (int i = 0; i < 4; ++i)
#pragma unroll
    for (int j = 0; j < 4; ++j) acc[i][j] = zero4;

  for (int k0 = 0; k0 < K; k0 += 32) {
#pragma unroll
    for (int c = 0; c < 4; ++c) {
      int row = rbase + c * 32;
      async16(emb + (size_t)trow[c] * EMBED + k0 + cs4,
              lAf + (size_t)(wave * 64 + c * 256) * 4);
      async16(convw + (size_t)(n0 + row) * K + k0 + cs4,
              lBf + (size_t)(wave * 64 + c * 256) * 4);
    }
    __syncthreads();

    bf16x8 a[4], b[4];
#pragma unroll
    for (int t = 0; t < 4; ++t) {
      a[t] = cvt8(lAf + (wm + t * 16 + lrow) * 32 + quad * 8);
      b[t] = cvt8(lBf + (wn + t * 16 + lrow) * 32 + quad * 8);
    }
#pragma unroll
    for (int mi = 0; mi < 4; ++mi)
#pragma unroll
      for (int ni = 0; ni < 4; ++ni)
        acc[mi][ni] =
            __builtin_amdgcn_mfma_f32_16x16x32_bf16(a[mi], b[ni], acc[mi][ni], 0, 0, 0);
    __syncthreads();
  }

#pragma unroll
  for (int mi = 0; mi < 4; ++mi) {
#pragma unroll
    for (int ni = 0; ni < 4; ++ni) {
      int col = n0 + wn + ni * 16 + lrow;
      float bv = bias[col];
#pragma unroll
      for (int r = 0; r < 4; ++r) {
        int row = m0 + wm + mi * 16 + quad * 4 + r;
        float v = acc[mi][ni][r] + bv;
        v = v > 0.f ? v : 0.f;
        out[(size_t)row * N + col] = (bf16)v;
      }
    }
  }
}

// ---- bf16 GEMM: C = act(A @ Bt^T + bias), 128x128 tile, templated BK -------
template <int BK, bool RELU, bool OUTBF>
__global__ __launch_bounds__(256) void gemm_bt(const bf16* __restrict__ A,
                                               const bf16* __restrict__ Bt,
                                               const float* __restrict__ bias,
                                               void* __restrict__ out,
                                               int M, int N, int K) {
  constexpr int GR = BK / 8;              // 16B granules per row
  constexpr int ISS = 128 * GR / 256;     // staging issues per operand
  __shared__ __attribute__((aligned(16))) bf16 lA[128 * BK];
  __shared__ __attribute__((aligned(16))) bf16 lB[128 * BK];
  const int tid = threadIdx.x;
  const int wave = tid >> 6, lane = tid & 63;
  const int m0 = blockIdx.x * 128, n0 = blockIdx.y * 128;
  const int wm = (wave & 1) * 64, wn = (wave >> 1) * 64;
  const int lrow = lane & 15, quad = lane >> 4;
  const int slot0 = wave * 64 + lane;

  const f32x4 zero4 = {0.f, 0.f, 0.f, 0.f};
  f32x4 acc[4][4];
#pragma unroll
  for (int i = 0; i < 4; ++i)
#pragma unroll
    for (int j = 0; j < 4; ++j) acc[i][j] = zero4;

  for (int k0 = 0; k0 < K; k0 += BK) {
#pragma unroll
    for (int c = 0; c < ISS; ++c) {
      int g = slot0 + c * 256;
      int row = g / GR, cs = g % GR;
      async16(A + (size_t)(m0 + row) * K + k0 + cs * 8,
              lA + (size_t)(wave * 64 + c * 256) * 8);
      async16(Bt + (size_t)(n0 + row) * K + k0 + cs * 8,
              lB + (size_t)(wave * 64 + c * 256) * 8);
    }
    __syncthreads();

#pragma unroll
    for (int ks = 0; ks < BK / 32; ++ks) {
      bf16x8 a[4], b[4];
#pragma unroll
      for (int t = 0; t < 4; ++t) {
        a[t] = *(const bf16x8*)(lA + (wm + t * 16 + lrow) * BK + ks * 32 + quad * 8);
        b[t] = *(const bf16x8*)(lB + (wn + t * 16 + lrow) * BK + ks * 32 + quad * 8);
      }
#pragma unroll
      for (int mi = 0; mi < 4; ++mi)
#pragma unroll
        for (int ni = 0; ni < 4; ++ni)
          acc[mi][ni] =
              __builtin_amdgcn_mfma_f32_16x16x32_bf16(a[mi], b[ni], acc[mi][ni], 0, 0, 0);
    }
    __syncthreads();
  }

#pragma unroll
  for (int mi = 0; mi < 4; ++mi) {
#pragma unroll
    for (int ni = 0; ni < 4; ++ni) {
      int col = n0 + wn + ni * 16 + lrow;
      float bv = bias[col];
#pragma unroll
      for (int r = 0; r < 4; ++r) {
        int row = m0 + wm + mi * 16 + quad * 4 + r;
        float v = acc[mi][ni][r] + bv;
        if (RELU) v = v > 0.f ? v : 0.f;
        if (OUTBF)
          ((bf16*)out)[(size_t)row * N + col] = (bf16)v;
        else
          ((float*)out)[(size_t)row * N + col] = v;
      }
    }
  }
}

// ---- layer 3: 64x128 tile (better occupancy at N=128), BK=32, f32 out ------
__global__ __launch_bounds__(256) void gemm_bt64(const bf16* __restrict__ A,
                                                 const bf16* __restrict__ Bt,
                                                 const float* __restrict__ bias,
                                                 float* __restrict__ out,
                                                 int M, int N, int K) {
  __shared__ __attribute__((aligned(16))) bf16 lA[64 * 32];
  __shared__ __attribute__((aligned(16))) bf16 lB[128 * 32];
  const int tid = threadIdx.x;
  const int wave = tid >> 6, lane = tid & 63;
  const int m0 = blockIdx.x * 64, n0 = 0;
  const int wm = (wave & 1) * 32, wn = (wave >> 1) * 64;
  const int lrow = lane & 15, quad = lane >> 4;
  const int slot0 = wave * 64 + lane;

  const f32x4 zero4 = {0.f, 0.f, 0.f, 0.f};
  f32x4 acc[2][4];
#pragma unroll
  for (int i = 0; i < 2; ++i)
#pragma unroll
    for (int j = 0; j < 4; ++j) acc[i][j] = zero4;

  for (int k0 = 0; k0 < K; k0 += 32) {
    {  // A: 64 rows x 4 granules = 256 -> one issue
      int row = slot0 >> 2, cs = slot0 & 3;
      async16(A + (size_t)(m0 + row) * K + k0 + cs * 8,
              lA + (size_t)(wave * 64) * 8);
    }
#pragma unroll
    for (int c = 0; c < 2; ++c) {  // B: 128 rows x 4 = 512 -> two issues
      int g = slot0 + c * 256;
      int row = g >> 2, cs = g & 3;
      async16(Bt + (size_t)(n0 + row) * K + k0 + cs * 8,
              lB + (size_t)(wave * 64 + c * 256) * 8);
    }
    __syncthreads();

    bf16x8 a[2], b[4];
#pragma unroll
    for (int t = 0; t < 2; ++t)
      a[t] = *(const bf16x8*)(lA + (wm + t * 16 + lrow) * 32 + quad * 8);
#pragma unroll
    for (int t = 0; t < 4; ++t)
      b[t] = *(const bf16x8*)(lB + (wn + t * 16 + lrow) * 32 + quad * 8);
#pragma unroll
    for (int mi = 0; mi < 2; ++mi)
#pragma unroll
      for (int ni = 0; ni < 4; ++ni)
        acc[mi][ni] =
            __builtin_amdgcn_mfma_f32_16x16x32_bf16(a[mi], b[ni], acc[mi][ni], 0, 0, 0);
    __syncthreads();
  }

#pragma unroll
  for (int mi = 0; mi < 2; ++mi) {
#pragma unroll
    for (int ni = 0; ni < 4; ++ni) {
      int col = n0 + wn + ni * 16 + lrow;
      float bv = bias[col];
#pragma unroll
      for (int r = 0; r < 4; ++r) {
        int row = m0 + wm + mi * 16 + quad * 4 + r;
        out[(size_t)row * N + col] = acc[mi][ni][r] + bv;
      }
    }
  }
}

// ---- launcher --------------------------------------------------------------

extern "C" void kernel_launch(void* const* d_in, const int* in_sizes, int n_in,
                              void* d_out, int out_size, void* d_ws, size_t ws_size,
                              hipStream_t stream) {
  const int* tok = (const int*)d_in[0];
  const float* emb = (const float*)d_in[1];
  const float* conv_w = (const float*)d_in[2];  // [512,512] = [N,K]
  const float* conv_b = (const float*)d_in[3];
  const float* w1 = (const float*)d_in[4];      // [512,1024] = [K,N]
  const float* b1 = (const float*)d_in[5];
  const float* w2 = (const float*)d_in[6];      // [1024,128] = [K,N]
  const float* b2 = (const float*)d_in[7];
  float* out = (float*)d_out;

  char* ws = (char*)d_ws;
  bf16* wt1 = (bf16*)(ws);                       // 1 MB    [1024,512]
  bf16* wt2 = (bf16*)(ws + (1u << 20));          // 256 KB  [128,1024]
  bf16* h = (bf16*)(ws + (2u << 20));            // 32 MB   [32768,512]
  bf16* z = (bf16*)(ws + (34u << 20));           // 64 MB   [32768,1024]

  // weight prep (transpose + bf16)
  hipLaunchKernelGGL(transpose_cvt, dim3(8, 16), dim3(256), 0, stream,
                     w1, wt1, CONV_C, HID);
  hipLaunchKernelGGL(transpose_cvt, dim3(16, 2), dim3(256), 0, stream,
                     w2, wt2, HID, LABELS);

  // layer 1 (gather fused): h = relu(emb[tok] @ conv_w^T + conv_b)
  hipLaunchKernelGGL(gemm1_gather, dim3(NROWS / 128, CONV_C / 128), dim3(256),
                     0, stream, tok, emb, conv_w, conv_b, h, NROWS, CONV_C, EMBED);
  // layer 2: z = relu(h @ w1 + b1)   BK=64
  hipLaunchKernelGGL((gemm_bt<64, true, true>), dim3(NROWS / 128, HID / 128), dim3(256),
                     0, stream, h, wt1, b1, (void*)z, NROWS, HID, CONV_C);
  // layer 3: out = z @ w2 + b2, 64-row tiles
  hipLaunchKernelGGL(gemm_bt64, dim3(NROWS / 64, 1), dim3(256),
                     0, stream, z, wt2, b2, out, NROWS, LABELS, HID);
}

// Round 3
// 270.297 us; speedup vs baseline: 1.0751x; 1.0751x over previous
//
#include <hip/hip_runtime.h>

typedef __bf16 bf16;
typedef __bf16 bf16x4 __attribute__((ext_vector_type(4)));
typedef __bf16 bf16x8 __attribute__((ext_vector_type(8)));
typedef float f32x4 __attribute__((ext_vector_type(4)));

#define NROWS 32768   // B*S = 32*1024
#define EMBED 512
#define CONV_C 512
#define HID 1024
#define LABELS 128

__device__ inline void async16(const void* g, void* l) {
  __builtin_amdgcn_global_load_lds(
      (const __attribute__((address_space(1))) void*)g,
      (__attribute__((address_space(3))) void*)l, 16, 0, 0);
}

// two 16B fp32 chunks (swizzled positions) -> bf16x8 fragment
__device__ inline bf16x8 cvt8_sw(const float* row, int o0, int o1) {
  f32x4 lo = *(const f32x4*)(row + o0);
  f32x4 hi = *(const f32x4*)(row + o1);
  bf16x8 r;
  r[0] = (bf16)lo[0]; r[1] = (bf16)lo[1]; r[2] = (bf16)lo[2]; r[3] = (bf16)lo[3];
  r[4] = (bf16)hi[0]; r[5] = (bf16)hi[1]; r[6] = (bf16)hi[2]; r[7] = (bf16)hi[3];
  return r;
}

// ---- prep kernels ----------------------------------------------------------

__global__ void cvt_bf16(const float* __restrict__ in, bf16* __restrict__ out, int n) {
  int i = (blockIdx.x * blockDim.x + threadIdx.x) * 4;
  if (i >= n) return;
  float4 v = *(const float4*)(in + i);
  bf16x4 o;
  o.x = (bf16)v.x; o.y = (bf16)v.y; o.z = (bf16)v.z; o.w = (bf16)v.w;
  *(bf16x4*)(out + i) = o;
}

// [K,N] f32 -> [N,K] bf16 transpose, 64x64 tiles
__global__ void transpose_cvt(const float* __restrict__ in, bf16* __restrict__ out,
                              int K, int N) {
  __shared__ float t[64][65];
  int kb = blockIdx.x * 64, nb = blockIdx.y * 64;
  for (int i = threadIdx.x; i < 4096; i += 256) {
    int r = i >> 6, c = i & 63;
    t[r][c] = in[(size_t)(kb + r) * N + nb + c];
  }
  __syncthreads();
  for (int i = threadIdx.x; i < 4096; i += 256) {
    int r = i >> 6, c = i & 63;
    out[(size_t)(nb + r) * K + kb + c] = (bf16)t[c][r];
  }
}

// ---- layer 1: h = relu(emb[tok] @ conv_w^T + conv_b), gather fused ---------
// A gathered from emb as fp32, staged with 16B-granule XOR swizzle
// (granule p of row r lives at p ^ (r&7)) -> uniform 8-access/bank reads.
// B = conv_w pre-converted bf16 [512,512] ([N,K]), conflict-minimal layout.
__global__ __launch_bounds__(256) void gemm1_gather(
    const int* __restrict__ tok, const float* __restrict__ emb,
    const bf16* __restrict__ convw, const float* __restrict__ bias,
    bf16* __restrict__ out, int M, int N, int K) {
  __shared__ __attribute__((aligned(16))) float lAf[128 * 32];  // 16 KB
  __shared__ __attribute__((aligned(16))) bf16 lB[128 * 32];    //  8 KB
  const int tid = threadIdx.x;
  const int wave = tid >> 6, lane = tid & 63;
  const int m0 = blockIdx.x * 128, n0 = blockIdx.y * 128;
  const int wm = (wave & 1) * 64, wn = (wave >> 1) * 64;
  const int lrow = lane & 15, quad = lane >> 4;
  const int slot0 = wave * 64 + lane;

  // A staging geometry: 1024 granule-slots (128 rows x 8), 4 issues/thread
  int arow[4], acol[4];
#pragma unroll
  for (int c = 0; c < 4; ++c) {
    int s = slot0 + c * 256;
    int r = s >> 3, p = s & 7;
    arow[c] = r;
    acol[c] = (p ^ (r & 7)) * 4;  // swizzled source column (floats)
  }
  int trow[4];
#pragma unroll
  for (int c = 0; c < 4; ++c) trow[c] = tok[m0 + arow[c]];

  const f32x4 zero4 = {0.f, 0.f, 0.f, 0.f};
  f32x4 acc[4][4];
#pragma unroll
  for (int i = 0; i < 4; ++i)
#pragma unroll
    for (int j = 0; j < 4; ++j) acc[i][j] = zero4;

  for (int k0 = 0; k0 < K; k0 += 32) {
#pragma unroll
    for (int c = 0; c < 4; ++c)
      async16(emb + (size_t)trow[c] * EMBED + k0 + acol[c],
              lAf + (size_t)(wave * 64 + c * 256) * 4);
#pragma unroll
    for (int c = 0; c < 2; ++c) {
      int s = slot0 + c * 256;
      int r = s >> 2, cs = s & 3;
      async16(convw + (size_t)(n0 + r) * K + k0 + cs * 8,
              lB + (size_t)(wave * 64 + c * 256) * 8);
    }
    __syncthreads();

    bf16x8 a[4], b[4];
#pragma unroll
    for (int t = 0; t < 4; ++t) {
      int r = wm + t * 16 + lrow, sw = r & 7;
      a[t] = cvt8_sw(lAf + r * 32, ((2 * quad) ^ sw) * 4, ((2 * quad + 1) ^ sw) * 4);
      b[t] = *(const bf16x8*)(lB + (wn + t * 16 + lrow) * 32 + quad * 8);
    }
#pragma unroll
    for (int mi = 0; mi < 4; ++mi)
#pragma unroll
      for (int ni = 0; ni < 4; ++ni)
        acc[mi][ni] =
            __builtin_amdgcn_mfma_f32_16x16x32_bf16(a[mi], b[ni], acc[mi][ni], 0, 0, 0);
    __syncthreads();
  }

#pragma unroll
  for (int mi = 0; mi < 4; ++mi) {
#pragma unroll
    for (int ni = 0; ni < 4; ++ni) {
      int col = n0 + wn + ni * 16 + lrow;
      float bv = bias[col];
#pragma unroll
      for (int r = 0; r < 4; ++r) {
        int row = m0 + wm + mi * 16 + quad * 4 + r;
        float v = acc[mi][ni][r] + bv;
        v = v > 0.f ? v : 0.f;
        out[(size_t)row * N + col] = (bf16)v;
      }
    }
  }
}

// ---- bf16 GEMM: C = act(A @ Bt^T + bias), 128x128 tile, BK=32 --------------
template <bool RELU, bool OUTBF>
__global__ __launch_bounds__(256) void gemm_bt(const bf16* __restrict__ A,
                                               const bf16* __restrict__ Bt,
                                               const float* __restrict__ bias,
                                               void* __restrict__ out,
                                               int M, int N, int K) {
  __shared__ __attribute__((aligned(16))) bf16 lA[128 * 32];
  __shared__ __attribute__((aligned(16))) bf16 lB[128 * 32];
  const int tid = threadIdx.x;
  const int wave = tid >> 6, lane = tid & 63;
  const int m0 = blockIdx.x * 128, n0 = blockIdx.y * 128;
  const int wm = (wave & 1) * 64, wn = (wave >> 1) * 64;
  const int lrow = lane & 15, quad = lane >> 4;
  const int slot0 = wave * 64 + lane;

  const f32x4 zero4 = {0.f, 0.f, 0.f, 0.f};
  f32x4 acc[4][4];
#pragma unroll
  for (int i = 0; i < 4; ++i)
#pragma unroll
    for (int j = 0; j < 4; ++j) acc[i][j] = zero4;

  for (int k0 = 0; k0 < K; k0 += 32) {
#pragma unroll
    for (int c = 0; c < 2; ++c) {
      int g = slot0 + c * 256;
      int row = g >> 2, cs = g & 3;
      async16(A + (size_t)(m0 + row) * K + k0 + cs * 8,
              lA + (size_t)(wave * 64 + c * 256) * 8);
      async16(Bt + (size_t)(n0 + row) * K + k0 + cs * 8,
              lB + (size_t)(wave * 64 + c * 256) * 8);
    }
    __syncthreads();

    bf16x8 a[4], b[4];
#pragma unroll
    for (int t = 0; t < 4; ++t) {
      a[t] = *(const bf16x8*)(lA + (wm + t * 16 + lrow) * 32 + quad * 8);
      b[t] = *(const bf16x8*)(lB + (wn + t * 16 + lrow) * 32 + quad * 8);
    }
#pragma unroll
    for (int mi = 0; mi < 4; ++mi)
#pragma unroll
      for (int ni = 0; ni < 4; ++ni)
        acc[mi][ni] =
            __builtin_amdgcn_mfma_f32_16x16x32_bf16(a[mi], b[ni], acc[mi][ni], 0, 0, 0);
    __syncthreads();
  }

#pragma unroll
  for (int mi = 0; mi < 4; ++mi) {
#pragma unroll
    for (int ni = 0; ni < 4; ++ni) {
      int col = n0 + wn + ni * 16 + lrow;
      float bv = bias[col];
#pragma unroll
      for (int r = 0; r < 4; ++r) {
        int row = m0 + wm + mi * 16 + quad * 4 + r;
        float v = acc[mi][ni][r] + bv;
        if (RELU) v = v > 0.f ? v : 0.f;
        if (OUTBF)
          ((bf16*)out)[(size_t)row * N + col] = (bf16)v;
        else
          ((float*)out)[(size_t)row * N + col] = v;
      }
    }
  }
}

// ---- layer 3: 64x128 tile, BK=32, f32 out ----------------------------------
__global__ __launch_bounds__(256) void gemm_bt64(const bf16* __restrict__ A,
                                                 const bf16* __restrict__ Bt,
                                                 const float* __restrict__ bias,
                                                 float* __restrict__ out,
                                                 int M, int N, int K) {
  __shared__ __attribute__((aligned(16))) bf16 lA[64 * 32];
  __shared__ __attribute__((aligned(16))) bf16 lB[128 * 32];
  const int tid = threadIdx.x;
  const int wave = tid >> 6, lane = tid & 63;
  const int m0 = blockIdx.x * 64, n0 = 0;
  const int wm = (wave & 1) * 32, wn = (wave >> 1) * 64;
  const int lrow = lane & 15, quad = lane >> 4;
  const int slot0 = wave * 64 + lane;

  const f32x4 zero4 = {0.f, 0.f, 0.f, 0.f};
  f32x4 acc[2][4];
#pragma unroll
  for (int i = 0; i < 2; ++i)
#pragma unroll
    for (int j = 0; j < 4; ++j) acc[i][j] = zero4;

  for (int k0 = 0; k0 < K; k0 += 32) {
    {
      int row = slot0 >> 2, cs = slot0 & 3;
      async16(A + (size_t)(m0 + row) * K + k0 + cs * 8,
              lA + (size_t)(wave * 64) * 8);
    }
#pragma unroll
    for (int c = 0; c < 2; ++c) {
      int g = slot0 + c * 256;
      int row = g >> 2, cs = g & 3;
      async16(Bt + (size_t)(n0 + row) * K + k0 + cs * 8,
              lB + (size_t)(wave * 64 + c * 256) * 8);
    }
    __syncthreads();

    bf16x8 a[2], b[4];
#pragma unroll
    for (int t = 0; t < 2; ++t)
      a[t] = *(const bf16x8*)(lA + (wm + t * 16 + lrow) * 32 + quad * 8);
#pragma unroll
    for (int t = 0; t < 4; ++t)
      b[t] = *(const bf16x8*)(lB + (wn + t * 16 + lrow) * 32 + quad * 8);
#pragma unroll
    for (int mi = 0; mi < 2; ++mi)
#pragma unroll
      for (int ni = 0; ni < 4; ++ni)
        acc[mi][ni] =
            __builtin_amdgcn_mfma_f32_16x16x32_bf16(a[mi], b[ni], acc[mi][ni], 0, 0, 0);
    __syncthreads();
  }

#pragma unroll
  for (int mi = 0; mi < 2; ++mi) {
#pragma unroll
    for (int ni = 0; ni < 4; ++ni) {
      int col = n0 + wn + ni * 16 + lrow;
      float bv = bias[col];
#pragma unroll
      for (int r = 0; r < 4; ++r) {
        int row = m0 + wm + mi * 16 + quad * 4 + r;
        out[(size_t)row * N + col] = acc[mi][ni][r] + bv;
      }
    }
  }
}

// ---- launcher --------------------------------------------------------------

extern "C" void kernel_launch(void* const* d_in, const int* in_sizes, int n_in,
                              void* d_out, int out_size, void* d_ws, size_t ws_size,
                              hipStream_t stream) {
  const int* tok = (const int*)d_in[0];
  const float* emb = (const float*)d_in[1];
  const float* conv_w = (const float*)d_in[2];  // [512,512] = [N,K]
  const float* conv_b = (const float*)d_in[3];
  const float* w1 = (const float*)d_in[4];      // [512,1024] = [K,N]
  const float* b1 = (const float*)d_in[5];
  const float* w2 = (const float*)d_in[6];      // [1024,128] = [K,N]
  const float* b2 = (const float*)d_in[7];
  float* out = (float*)d_out;

  char* ws = (char*)d_ws;
  bf16* wtc = (bf16*)(ws);                       // 512 KB [512,512]
  bf16* wt1 = (bf16*)(ws + (1u << 19));          // 1 MB   [1024,512]
  bf16* wt2 = (bf16*)(ws + 3 * (1u << 19));      // 256 KB [128,1024]
  bf16* h = (bf16*)(ws + (2u << 20));            // 32 MB  [32768,512]
  bf16* z = (bf16*)(ws + (34u << 20));           // 64 MB  [32768,1024]

  // weight prep
  hipLaunchKernelGGL(cvt_bf16, dim3(256), dim3(256), 0, stream,
                     conv_w, wtc, CONV_C * EMBED);
  hipLaunchKernelGGL(transpose_cvt, dim3(8, 16), dim3(256), 0, stream,
                     w1, wt1, CONV_C, HID);
  hipLaunchKernelGGL(transpose_cvt, dim3(16, 2), dim3(256), 0, stream,
                     w2, wt2, HID, LABELS);

  // layer 1 (gather fused, swizzled fp32 A staging)
  hipLaunchKernelGGL(gemm1_gather, dim3(NROWS / 128, CONV_C / 128), dim3(256),
                     0, stream, tok, emb, wtc, conv_b, h, NROWS, CONV_C, EMBED);
  // layer 2: z = relu(h @ w1 + b1), BK=32 (conflict-minimal)
  hipLaunchKernelGGL((gemm_bt<true, true>), dim3(NROWS / 128, HID / 128), dim3(256),
                     0, stream, h, wt1, b1, (void*)z, NROWS, HID, CONV_C);
  // layer 3: out = z @ w2 + b2
  hipLaunchKernelGGL(gemm_bt64, dim3(NROWS / 64, 1), dim3(256),
                     0, stream, z, wt2, b2, out, NROWS, LABELS, HID);
}